// Round 2
// baseline (404.450 us; speedup 1.0000x reference)
//
#include <hip/hip_runtime.h>
#include <math.h>

// TemporalSNNClassifier — bit-exact float32 emulation of the numpy reference.
//
// Evidence (round 1): exact-fp64 kernel fails by single spike flips (absmax
// 1.0) -> the np reference is float32. We reproduce fp32 rounding exactly:
//  - GEMMs as single k-ascending fmaf chains from 0 (BLAS microkernel order),
//    bias added as one separate rounded add.
//  - Leaky updates with numpy op order, contraction disabled:
//      mem = ((0.9f*mem) + cur) - reset ;  spk = (mem - 1.0f > 0)
//  - reset_t == spk_{t-1} (subtract reset, THRESH=1).
//  - Layer-2 chain h=0..127 strictly sequential per (row,class); spikes enter
//    as 0.0f/1.0f — fmaf(s,w,acc) is bit-identical to BLAS's fma.

#define T_STEPS 64
#define IN_DIM  256
#define HID     128
#define NCLS    8
#define RPB     64    // rows per block
#define NTHR    512   // 8 waves

__global__ __launch_bounds__(NTHR, 2)
void snn_fp32(const float* __restrict__ x, const float* __restrict__ W1,
              const float* __restrict__ b1, const float* __restrict__ W2,
              const float* __restrict__ b2, float* __restrict__ out)
{
#pragma clang fp contract(off)
    __shared__ unsigned short smask[RPB * 8];   // [row][q]: 16 spike bits each

    const int tid = threadIdx.x;
    const int r   = tid >> 3;            // local row, phase a
    const int q   = tid & 7;             // h-block (16 contiguous h)
    const int row = blockIdx.x * RPB + r;

    // ---- cur1[h] = fmaf-chain_k( x[row,k] * W1[h,k] ) + b1[h], h=q*16+i ----
    float cur1[16];
    #pragma unroll
    for (int i = 0; i < 16; ++i) cur1[i] = 0.0f;

    const float* xrow = x + (size_t)row * IN_DIM;
    const float* w1b  = W1 + (size_t)(q * 16) * IN_DIM;
    for (int k = 0; k < IN_DIM; k += 4) {
        const float4 xv = *(const float4*)(xrow + k);
        #pragma unroll
        for (int i = 0; i < 16; ++i) {
            const float4 wv = *(const float4*)(w1b + i * IN_DIM + k);
            float c = cur1[i];
            c = fmaf(xv.x, wv.x, c);     // k ascending, single accumulator
            c = fmaf(xv.y, wv.y, c);
            c = fmaf(xv.z, wv.z, c);
            c = fmaf(xv.w, wv.w, c);
            cur1[i] = c;
        }
    }
    #pragma unroll
    for (int i = 0; i < 16; ++i)
        cur1[i] = cur1[i] + b1[q * 16 + i];   // one rounded add (numpy +b1)

    float mem1[16], spk1[16];
    #pragma unroll
    for (int i = 0; i < 16; ++i) { mem1[i] = 0.0f; spk1[i] = 0.0f; }

    // ---- phase-b role: waves 0..3, wave w -> classes {2w, 2w+1}, lane=row --
    const int wq = __builtin_amdgcn_readfirstlane((int)(threadIdx.x >> 6));
    const int ln = tid & 63;
    const bool bwave = (wq < 4);
    const int c0 = bwave ? 2 * wq : 0;
    const float* __restrict__ W2a = W2 + (size_t)c0 * HID;
    const float* __restrict__ W2b = W2 + (size_t)(c0 + 1) * HID;
    float b2a = 0.0f, b2b = 0.0f;
    if (bwave) { b2a = b2[c0]; b2b = b2[c0 + 1]; }
    float m2a = 0.0f, m2b = 0.0f;   // mem2 for the two classes
    float r2a = 0.0f, r2b = 0.0f;   // spk2 (== next reset)
    float oa  = 0.0f, ob  = 0.0f;   // output accumulators

    for (int t = 0; t < T_STEPS; ++t) {
        // phase a: leaky layer-1 update, numpy rounding order, no contraction
        unsigned int mk = 0;
        #pragma unroll
        for (int i = 0; i < 16; ++i) {
            float tmp = 0.9f * mem1[i];   // rounded mul
            tmp = tmp + cur1[i];          // rounded add
            float m = tmp - spk1[i];      // rounded sub (reset*1.0 == reset)
            mem1[i] = m;
            float u = m - 1.0f;           // spike(mem - THRESH)
            bool fire = (u > 0.0f);
            spk1[i] = fire ? 1.0f : 0.0f;
            mk |= fire ? (1u << i) : 0u;
        }
        smask[r * 8 + q] = (unsigned short)mk;
        __syncthreads();

        if (bwave) {
            // cur2[c] = fmaf-chain_h( s_h * W2[c,h] ) + b2[c], h ascending
            const uint4 mv = *(const uint4*)&smask[ln * 8];
            unsigned int mw[4] = {mv.x, mv.y, mv.z, mv.w};
            float a0 = 0.0f, a1 = 0.0f;
            #pragma unroll
            for (int j = 0; j < 4; ++j) {
                const unsigned int m = mw[j];
                #pragma unroll
                for (int b = 0; b < 32; ++b) {
                    const int h = j * 32 + b;
                    const float s = (float)((m >> b) & 1u);
                    a0 = fmaf(s, W2a[h], a0);
                    a1 = fmaf(s, W2b[h], a1);
                }
            }
            const float c2a = a0 + b2a;
            const float c2b = a1 + b2b;
            float ta = 0.9f * m2a; ta = ta + c2a; m2a = ta - r2a;
            float tb = 0.9f * m2b; tb = tb + c2b; m2b = tb - r2b;
            r2a = ((m2a - 1.0f) > 0.0f) ? 1.0f : 0.0f;
            r2b = ((m2b - 1.0f) > 0.0f) ? 1.0f : 0.0f;
            oa = oa + r2a;                // acc += spk2 (exact, <=64)
            ob = ob + r2b;
        }
        __syncthreads();   // protect smask for next step
    }

    if (bwave) {
        float2 v = make_float2(oa, ob);
        *(float2*)(out + (size_t)(blockIdx.x * RPB + ln) * NCLS + c0) = v;
    }
}

extern "C" void kernel_launch(void* const* d_in, const int* in_sizes, int n_in,
                              void* d_out, int out_size, void* d_ws, size_t ws_size,
                              hipStream_t stream) {
    const float* x  = (const float*)d_in[0];
    const float* W1 = (const float*)d_in[1];
    const float* b1 = (const float*)d_in[2];
    const float* W2 = (const float*)d_in[3];
    const float* b2 = (const float*)d_in[4];
    float* out = (float*)d_out;

    const int batch = in_sizes[0] / IN_DIM;   // 16384
    const int grid  = batch / RPB;            // 256 blocks
    snn_fp32<<<grid, NTHR, 0, stream>>>(x, W1, b1, W2, b2, out);
}